// Round 1
// baseline (173.224 us; speedup 1.0000x reference)
//
#include <hip/hip_runtime.h>

// E3Hamiltonian spin projection: fixed 4x4 complex mix over channel dim.
// Input/Output: [B=65536, C=8, nL=13, nR=13] float32, channel layout
// [r0 r1 r2 r3 | i0 i1 i2 i3] (complex-doubled real storage).
//
// Per (n, l, r) site:
//   o0 = (r0 + i? ...)  -- see derivation in journal; 1/sqrt(2) scale.
//
// Memory-bound: 709 MB total traffic -> ~112 us at 6.3 TB/s.

#define PLANE 169          // nL*nR = 13*13
#define CSTRIDE 1352       // 8 * PLANE, floats per batch item

__constant__ float kInvSqrt2 = 0.70710678118654752440f;

__global__ __launch_bounds__(256) void spin_proj_kernel(
    const float* __restrict__ in, float* __restrict__ out, int total_sites) {
    int idx = blockIdx.x * blockDim.x + threadIdx.x;
    if (idx >= total_sites) return;

    // idx = n * PLANE + j
    int n = idx / PLANE;
    int j = idx - n * PLANE;

    const float* ib = in + (size_t)n * CSTRIDE + j;
    float r0 = ib[0 * PLANE];
    float r1 = ib[1 * PLANE];
    float r2 = ib[2 * PLANE];
    float r3 = ib[3 * PLANE];
    float i0 = ib[4 * PLANE];
    float i1 = ib[5 * PLANE];
    float i2 = ib[6 * PLANE];
    float i3 = ib[7 * PLANE];

    const float s = 0.70710678118654752440f;
    float* ob = out + (size_t)n * CSTRIDE + j;
    // real halves of (uu, ud, du, dd)
    ob[0 * PLANE] = (r0 + r2) * s;
    ob[1 * PLANE] = (i1 + r3) * s;
    ob[2 * PLANE] = (r3 - i1) * s;
    ob[3 * PLANE] = (r0 - r2) * s;
    // imag halves
    ob[4 * PLANE] = (i0 + i2) * s;
    ob[5 * PLANE] = (i3 - r1) * s;
    ob[6 * PLANE] = (r1 + i3) * s;
    ob[7 * PLANE] = (i0 - i2) * s;
}

extern "C" void kernel_launch(void* const* d_in, const int* in_sizes, int n_in,
                              void* d_out, int out_size, void* d_ws, size_t ws_size,
                              hipStream_t stream) {
    const float* in = (const float*)d_in[0];
    float* out = (float*)d_out;

    // in_sizes[0] = B * 8 * 169; sites = B * 169
    int total_sites = in_sizes[0] / 8;

    const int block = 256;
    int grid = (total_sites + block - 1) / block;
    spin_proj_kernel<<<grid, block, 0, stream>>>(in, out, total_sites);
}

// Round 2
// 138.472 us; speedup vs baseline: 1.2510x; 1.2510x over previous
//
#include <hip/hip_runtime.h>

// E3Hamiltonian spin projection: fixed 4x4 complex mix over channel dim.
// [B=65536, C=8, nL*nR=169] f32. Channel layout [r0 r1 r2 r3 | i0 i1 i2 i3].
//
// Round-2 strategy: odd PLANE=169 stride defeats in-place vectorization, so
// stage whole batch-item slabs (contiguous 1352 floats, 16B-aligned) into LDS
// with float4 loads, mix channels in LDS (stride-1 per wave -> conflict-free),
// stream back with float4 stores. Global access = 16B/lane coalesced both ways.

#define PLANE 169            // nL*nR
#define CSTRIDE 1352         // 8*PLANE floats per batch item
#define IPB 4                // batch items per block (65536 % 4 == 0)
#define SLAB_F (IPB * CSTRIDE)   // 5408 floats = 21632 B LDS
#define SLAB_V (SLAB_F / 4)      // 1352 float4
#define SITES (IPB * PLANE)      // 676 sites per block

__global__ __launch_bounds__(256) void spin_proj_kernel(
    const float4* __restrict__ in, float4* __restrict__ out) {
    __shared__ float lds[SLAB_F];
    float4* lds4 = (float4*)lds;

    const size_t base = (size_t)blockIdx.x * SLAB_V;
    const int t = threadIdx.x;

    // Stage: global -> LDS, coalesced dwordx4 (5408B/item aligned to 16B).
    #pragma unroll
    for (int k = 0; k < 6; ++k) {
        int v = t + k * 256;
        if (v < SLAB_V) lds4[v] = in[base + v];
    }
    __syncthreads();

    // Gather all 8 channel values per site into registers (reads complete
    // before any in-place writes via the barrier below).
    float vals[3][8];
    #pragma unroll
    for (int k = 0; k < 3; ++k) {
        int s = t + k * 256;
        if (s < SITES) {
            int item = s / PLANE;
            int j = s - item * PLANE;
            const float* p = lds + item * CSTRIDE + j;
            #pragma unroll
            for (int c = 0; c < 8; ++c) vals[k][c] = p[c * PLANE];
        }
    }
    __syncthreads();

    // Mix + write back in place.
    const float sc = 0.70710678118654752440f;
    #pragma unroll
    for (int k = 0; k < 3; ++k) {
        int s = t + k * 256;
        if (s < SITES) {
            int item = s / PLANE;
            int j = s - item * PLANE;
            float* p = lds + item * CSTRIDE + j;
            float r0 = vals[k][0], r1 = vals[k][1], r2 = vals[k][2], r3 = vals[k][3];
            float i0 = vals[k][4], i1 = vals[k][5], i2 = vals[k][6], i3 = vals[k][7];
            p[0 * PLANE] = (r0 + r2) * sc;   // uu.re
            p[1 * PLANE] = (i1 + r3) * sc;   // ud.re
            p[2 * PLANE] = (r3 - i1) * sc;   // du.re
            p[3 * PLANE] = (r0 - r2) * sc;   // dd.re
            p[4 * PLANE] = (i0 + i2) * sc;   // uu.im
            p[5 * PLANE] = (i3 - r1) * sc;   // ud.im
            p[6 * PLANE] = (r1 + i3) * sc;   // du.im
            p[7 * PLANE] = (i0 - i2) * sc;   // dd.im
        }
    }
    __syncthreads();

    // Drain: LDS -> global, coalesced dwordx4.
    #pragma unroll
    for (int k = 0; k < 6; ++k) {
        int v = t + k * 256;
        if (v < SLAB_V) out[base + v] = lds4[v];
    }
}

extern "C" void kernel_launch(void* const* d_in, const int* in_sizes, int n_in,
                              void* d_out, int out_size, void* d_ws, size_t ws_size,
                              hipStream_t stream) {
    const float4* in = (const float4*)d_in[0];
    float4* out = (float4*)d_out;

    // in_sizes[0] = B * CSTRIDE; blocks = B / IPB
    int n_items = in_sizes[0] / CSTRIDE;
    int grid = n_items / IPB;
    spin_proj_kernel<<<grid, 256, 0, stream>>>(in, out);
}

// Round 3
// 134.642 us; speedup vs baseline: 1.2866x; 1.0285x over previous
//
#include <hip/hip_runtime.h>

// E3Hamiltonian spin projection: fixed 4x4 complex mix over channel dim.
// [B=65536, C=8, nL*nR=169] f32. Channel layout [r0 r1 r2 r3 | i0 i1 i2 i3].
//
// Round-3 strategy: wave-private LDS slabs, zero s_barriers.
// Each 64-lane wave owns one batch item (1352 floats = 5408 B, contiguous):
//   stage (float4 coalesced) -> in-slab channel mix (stride-1, conflict-free)
//   -> drain (float4 coalesced). Cross-phase ordering is within-wave only,
// enforced by lgkmcnt waits (which the data dependence requires anyway), so
// waves never barrier-couple and HBM requests flow continuously.

#define PLANE 169            // nL*nR
#define CSTRIDE 1352         // 8*PLANE floats per item
#define QUADS 338            // float4 per item
#define WAVES 4              // waves (= items) per block

__global__ __launch_bounds__(256) void spin_proj_kernel(
    const float4* __restrict__ in, float4* __restrict__ out) {
    __shared__ float lds[WAVES * CSTRIDE];   // 21632 B -> 7 blocks/CU

    const int wave = threadIdx.x >> 6;
    const int lane = threadIdx.x & 63;
    float* slab = lds + wave * CSTRIDE;
    float4* slab4 = (float4*)slab;

    const size_t item = (size_t)blockIdx.x * WAVES + wave;
    const float4* __restrict__ gin = in + item * QUADS;
    float4* __restrict__ gout = out + item * QUADS;

    // Stage: global -> LDS, 16B/lane coalesced (338 quads, 6 ragged iters).
    #pragma unroll
    for (int k = 0; k < 6; ++k) {
        int v = lane + k * 64;
        if (v < QUADS) slab4[v] = gin[v];
    }
    asm volatile("s_waitcnt lgkmcnt(0)" ::: "memory");
    __builtin_amdgcn_wave_barrier();

    // Mix in place. Site j handled entirely by one lane -> no cross-lane
    // hazard; per-lane read-then-write same addresses is program-ordered.
    const float sc = 0.70710678118654752440f;
    #pragma unroll
    for (int k = 0; k < 3; ++k) {
        int j = lane + k * 64;
        if (j < PLANE) {
            float r0 = slab[0 * PLANE + j];
            float r1 = slab[1 * PLANE + j];
            float r2 = slab[2 * PLANE + j];
            float r3 = slab[3 * PLANE + j];
            float i0 = slab[4 * PLANE + j];
            float i1 = slab[5 * PLANE + j];
            float i2 = slab[6 * PLANE + j];
            float i3 = slab[7 * PLANE + j];
            slab[0 * PLANE + j] = (r0 + r2) * sc;   // uu.re
            slab[1 * PLANE + j] = (i1 + r3) * sc;   // ud.re
            slab[2 * PLANE + j] = (r3 - i1) * sc;   // du.re
            slab[3 * PLANE + j] = (r0 - r2) * sc;   // dd.re
            slab[4 * PLANE + j] = (i0 + i2) * sc;   // uu.im
            slab[5 * PLANE + j] = (i3 - r1) * sc;   // ud.im
            slab[6 * PLANE + j] = (r1 + i3) * sc;   // du.im
            slab[7 * PLANE + j] = (i0 - i2) * sc;   // dd.im
        }
    }
    asm volatile("s_waitcnt lgkmcnt(0)" ::: "memory");
    __builtin_amdgcn_wave_barrier();

    // Drain: LDS -> global, 16B/lane coalesced.
    #pragma unroll
    for (int k = 0; k < 6; ++k) {
        int v = lane + k * 64;
        if (v < QUADS) gout[v] = slab4[v];
    }
}

extern "C" void kernel_launch(void* const* d_in, const int* in_sizes, int n_in,
                              void* d_out, int out_size, void* d_ws, size_t ws_size,
                              hipStream_t stream) {
    const float4* in = (const float4*)d_in[0];
    float4* out = (float4*)d_out;

    int n_items = in_sizes[0] / CSTRIDE;     // 65536
    int grid = n_items / WAVES;              // 16384 blocks
    spin_proj_kernel<<<grid, 256, 0, stream>>>(in, out);
}